// Round 7
// baseline (135.661 us; speedup 1.0000x reference)
//
#include <hip/hip_runtime.h>
#include <hip/hip_bf16.h>

// MultiHeadAttention_66340064854505 — MI355X/gfx950
// B=1, N=4096, E=512, H=8, dk=64, WS=128, NDIM=16.
// ALL inputs/outputs FP32 (reference dtype). MFMA path converts to bf16.
//
// Identity (multiplicative block-causal mask into FULL-row softmax):
//   masked entries contribute exp(0)=1, so
//   out[i] = (Sum_{j<=i in blk}(e^s-1) v_j + V_total) / (Sum_{j<=i in blk}(e^s-1) + N)
// V_total via colsum identity: Sum_rows(x@Wv+b) = (Sum_rows x)@Wv + N*b.
// CEMA: 3-level scan (chunk 32 / group 16 / groups 8), fp32 exact; B2 inlined in passC.
// 5 dispatches: memset, L1(prep||passA), L2(qkvGEMM||passB1||vtot), L3(attn||passC), L4(outGEMM).
// R7: GEMMs use BK=64 (half the barrier pairs); L4 retiled to 128x64 (1 block/CU even).

typedef __bf16 bf16x8 __attribute__((ext_vector_type(8)));
typedef float  f32x4  __attribute__((ext_vector_type(4)));

#define N_TOK   4096
#define EDIM    512
#define DKH     64
#define WSZ     128
#define QKV_LD  1536
#define CCH     128   // CEMA chunks
#define CLEN    32    // CEMA chunk length

__device__ __forceinline__ void glds16(const void* gsrc, void* ldst) {
  __builtin_amdgcn_global_load_lds(
      (const __attribute__((address_space(1))) void*)gsrc,
      (__attribute__((address_space(3))) void*)ldst,
      16, 0, 0);
}

// ---------------- shared GEMM body: C[M,N] = A[M,K](bf16) * Bt[N,K]^T + bias(f32) ----------------
// 256 thr = 4 waves tiled (BM/WM)x(BN/WN) (must be 4). 16x16x32 bf16 MFMA, BK=64
// (2 MFMA k-steps per barrier pair -> half the syncthreads/vmcnt drains of BK=32).
// MODE 0: store bf16 to Cb.  MODE 1: store f32 w0*(gemm+bias)+w1*cema to Cf.
template <int MODE, int BM, int BN, int WM, int WN>
__device__ __forceinline__ void gemm_body(const __bf16* __restrict__ A,
                                          const __bf16* __restrict__ Bt,
                                          const float* __restrict__ bias,
                                          __bf16* __restrict__ Cb,
                                          float* __restrict__ Cf,
                                          int K, int ldc,
                                          const float* __restrict__ cema,
                                          const float* __restrict__ aw,
                                          int bx, int by, int t) {
  __shared__ __bf16 As[BM * 64];
  __shared__ __bf16 Bs[BN * 64];
  const int lane = t & 63, wid = t >> 6;
  const int quad = lane >> 4, c16 = lane & 15;
  const int wm = (wid % (BM / WM)) * WM, wn = (wid / (BM / WM)) * WN;
  const int m0 = bx * BM, n0 = by * BN;

  f32x4 acc[WM / 16][WN / 16] = {};

  // staging: thread t covers row (i*32 + t>>3), k-cols (t&7)*8..+8 of a 64-wide panel.
  // LDS offset i*2048 + t*8 == row-major [row][k], per-wave base uniform (glds constraint).
  const int ar = t >> 3, ac = (t & 7) * 8;
  const __bf16* gA = A + (size_t)(m0 + ar) * K + ac;
  const __bf16* gB = Bt + (size_t)(n0 + ar) * K + ac;

  for (int k0 = 0; k0 < K; k0 += 64) {
#pragma unroll
    for (int i = 0; i < BM / 32; i++)
      glds16(gA + (size_t)i * 32 * K + k0, As + i * 2048 + t * 8);
#pragma unroll
    for (int i = 0; i < BN / 32; i++)
      glds16(gB + (size_t)i * 32 * K + k0, Bs + i * 2048 + t * 8);
    __syncthreads();
#pragma unroll
    for (int kq = 0; kq < 2; kq++) {
      bf16x8 af[WM / 16], bf[WN / 16];
#pragma unroll
      for (int i = 0; i < WM / 16; i++)
        af[i] = *(const bf16x8*)&As[(wm + i * 16 + c16) * 64 + kq * 32 + quad * 8];
#pragma unroll
      for (int i = 0; i < WN / 16; i++)
        bf[i] = *(const bf16x8*)&Bs[(wn + i * 16 + c16) * 64 + kq * 32 + quad * 8];
#pragma unroll
      for (int mi = 0; mi < WM / 16; mi++)
#pragma unroll
        for (int ni = 0; ni < WN / 16; ni++)
          acc[mi][ni] = __builtin_amdgcn_mfma_f32_16x16x32_bf16(af[mi], bf[ni], acc[mi][ni], 0, 0, 0);
    }
    __syncthreads();
  }

  float w0 = 1.f, w1 = 0.f;
  if (MODE == 1) {
    float a0 = aw[0], a1 = aw[1];
    float mx = fmaxf(a0, a1);
    float e0 = __expf(a0 - mx), e1 = __expf(a1 - mx);
    w0 = e0 / (e0 + e1);
    w1 = 1.f - w0;
  }
#pragma unroll
  for (int mi = 0; mi < WM / 16; mi++) {
#pragma unroll
    for (int ni = 0; ni < WN / 16; ni++) {
      const int col = n0 + wn + ni * 16 + c16;
      const float bv = bias[col];
#pragma unroll
      for (int r = 0; r < 4; r++) {
        const int row = m0 + wm + mi * 16 + quad * 4 + r;
        float v = acc[mi][ni][r] + bv;
        if (MODE == 1) {
          v = w0 * v + w1 * cema[(size_t)row * EDIM + col];
          Cf[(size_t)row * ldc + col] = v;
        } else {
          Cb[(size_t)row * ldc + col] = (__bf16)v;
        }
      }
    }
  }
}

// ================= L1: weight prep (blocks 0..255) || CEMA passA (blocks 256..511) =================
__global__ __launch_bounds__(256) void fused_prep_cemaA(const float* __restrict__ Wq,
                                                        __bf16* __restrict__ WtQ,
                                                        const float* __restrict__ Wo,
                                                        __bf16* __restrict__ WtO,
                                                        const float* __restrict__ x,
                                                        const float* __restrict__ pc,
                                                        const float* __restrict__ qc,
                                                        float* __restrict__ h_end,
                                                        __bf16* __restrict__ x_bf,
                                                        float* __restrict__ xsum) {
  const int b = blockIdx.x, t = threadIdx.x;
  if (b < 256) {
    // transpose+convert fp32 RxC -> bf16 CxR, 64x64 tiles. bx<24: W_qkv, else W_out.
    __shared__ float tile[64][65];
    int bx = b & 31;
    const int by = b >> 5;
    const float* in;
    __bf16* out;
    int C;
    if (bx < 24) { in = Wq; out = WtQ; C = 1536; }
    else         { bx -= 24; in = Wo; out = WtO; C = 512; }
    const int R = 512;
#pragma unroll
    for (int i = 0; i < 16; i++) {
      int idx = t + i * 256;
      int r = idx >> 6, c = idx & 63;
      tile[r][c] = in[(size_t)(by * 64 + r) * C + bx * 64 + c];
    }
    __syncthreads();
#pragma unroll
    for (int i = 0; i < 16; i++) {
      int idx = t + i * 256;
      int r = idx >> 6, c = idx & 63;
      out[(size_t)(bx * 64 + r) * R + by * 64 + c] = (__bf16)tile[c][r];
    }
  } else {
    // CEMA passA: chunk-local scan; also emits x_bf and xsum.
    const int bb = b - 256;
    const int c = bb >> 1;
    const int e = ((bb & 1) << 8) + t;
    float p[16], q[16], h[16];
#pragma unroll
    for (int d4 = 0; d4 < 4; d4++) {
      const float4 pv = ((const float4*)(pc + e * 16))[d4];
      const float4 qv = ((const float4*)(qc + e * 16))[d4];
      p[d4 * 4 + 0] = pv.x; p[d4 * 4 + 1] = pv.y; p[d4 * 4 + 2] = pv.z; p[d4 * 4 + 3] = pv.w;
      q[d4 * 4 + 0] = qv.x; q[d4 * 4 + 1] = qv.y; q[d4 * 4 + 2] = qv.z; q[d4 * 4 + 3] = qv.w;
    }
#pragma unroll
    for (int d = 0; d < 16; d++) h[d] = 0.f;
    const float* xp = x + (size_t)c * CLEN * EDIM + e;
    __bf16* xb = x_bf + (size_t)c * CLEN * EDIM + e;
    float sx = 0.f;
#pragma unroll 4
    for (int tt = 0; tt < CLEN; tt++) {
      const float xv = xp[(size_t)tt * EDIM];
      xb[(size_t)tt * EDIM] = (__bf16)xv;
      sx += xv;
#pragma unroll
      for (int d = 0; d < 16; d++) h[d] = fmaf(p[d], xv, q[d] * h[d]);
    }
    atomicAdd(&xsum[e], sx);
    float* o = h_end + (size_t)c * 8192 + e * 16;
#pragma unroll
    for (int d = 0; d < 16; d++) o[d] = h[d];
  }
}

// ======= L2: QKV GEMM (0..383) || CEMA passB1 (384..639) || vtot (640..767) =======
__global__ __launch_bounds__(256) void fused_qkv_scan_vtot(const __bf16* __restrict__ x_bf,
                                                           const __bf16* __restrict__ WtQ,
                                                           const float* __restrict__ b_qkv,
                                                           __bf16* __restrict__ qkv,
                                                           const float* __restrict__ qc,
                                                           const float* __restrict__ h_end,
                                                           float* __restrict__ hin,
                                                           float* __restrict__ T,
                                                           const float* __restrict__ xsum,
                                                           float* __restrict__ vtot) {
  const int b = blockIdx.x, t = threadIdx.x;
  if (b < 384) {
    // M=4096 N=1536 K=512, BM=BN=128 -> 32 x 12 tiles
    gemm_body<0, 128, 128, 64, 64>(x_bf, WtQ, b_qkv, qkv, nullptr,
                                   EDIM, QKV_LD, nullptr, nullptr,
                                   b & 31, b >> 5, t);
  } else if (b < 640) {
    // passB1: per (group g of 16 chunks, channel i) local scan -> hin prefix + group total T
    const int idx = (b - 384) * 256 + t;  // 0..65535
    const int g = idx >> 13;              // 0..7
    const int i = idx & 8191;
    const float q = qc[i];
    float Q = q * q; Q = Q * Q; Q = Q * Q; Q = Q * Q; Q = Q * Q;  // q^32
    float L = 0.f;
    const int c0 = g * 16;
#pragma unroll 4
    for (int j = 0; j < 16; j++) {
      hin[(size_t)(c0 + j) * 8192 + i] = L;
      L = h_end[(size_t)(c0 + j) * 8192 + i] + Q * L;
    }
    T[(size_t)g * 8192 + i] = L;
  } else {
    // vtot[c] = dot(WtQ[1024+c][:], xsum) + N*b_qkv[1024+c]
    const int wid = t >> 6, lane = t & 63;
    const int c = (b - 640) * 4 + wid;  // [0,512)
    const bf16x8 wv = *(const bf16x8*)(WtQ + (size_t)(1024 + c) * 512 + lane * 8);
    const float4 x0 = *(const float4*)(xsum + lane * 8);
    const float4 x1 = *(const float4*)(xsum + lane * 8 + 4);
    float s = (float)wv[0] * x0.x + (float)wv[1] * x0.y + (float)wv[2] * x0.z + (float)wv[3] * x0.w
            + (float)wv[4] * x1.x + (float)wv[5] * x1.y + (float)wv[6] * x1.z + (float)wv[7] * x1.w;
#pragma unroll
    for (int m = 1; m < 64; m <<= 1) s += __shfl_xor(s, m);
    if (lane == 0) vtot[c] = s + (float)N_TOK * b_qkv[1024 + c];
  }
}

// ================= L3: attention (blocks 0..255) || CEMA passC+B2 (256..511) =================
__global__ __launch_bounds__(256) void fused_attn_cemaC(const __bf16* __restrict__ qkv,
                                                        const float* __restrict__ vtot,
                                                        __bf16* __restrict__ out_attn,
                                                        const float* __restrict__ x,
                                                        const float* __restrict__ pc,
                                                        const float* __restrict__ qc,
                                                        const float* __restrict__ gma,
                                                        const float* __restrict__ hin,
                                                        const float* __restrict__ T,
                                                        float* __restrict__ y) {
  const int b = blockIdx.x, t = threadIdx.x;
  if (b < 256) {
    // ---- block-local attention, one block per (window, head) ----
    // LDS (48.5 KB): phase1 Qs[0,16K) Ks[16K,32K); phase2 Ws[0,32K) Vt[32K,48K) rowsum[48K,48.5K)
    __shared__ float4 smem4[3104];
    __bf16* Qs = (__bf16*)smem4;
    __bf16* Ks = (__bf16*)smem4 + 8192;
    __bf16* Ws = (__bf16*)smem4;
    __bf16* Vt = (__bf16*)smem4 + 16384;
    float* rowsum = (float*)((__bf16*)smem4 + 24576);

    const int lane = t & 63, wid = t >> 6;
    const int quad = lane >> 4, c16 = lane & 15;
    const int h = b & 7, w = b >> 3;
    const size_t base = (size_t)w * WSZ * QKV_LD + h * DKH;

    const int sr = t >> 3, sc = (t & 7) * 8;
#pragma unroll
    for (int i = 0; i < 4; i++) {
      glds16(qkv + base + (size_t)(i * 32 + sr) * QKV_LD + sc,        Qs + i * 2048 + t * 8);
      glds16(qkv + base + EDIM + (size_t)(i * 32 + sr) * QKV_LD + sc, Ks + i * 2048 + t * 8);
    }
    __syncthreads();

    const int wm = (wid & 1) * 64, wn = (wid >> 1) * 64;
    f32x4 accs[4][4] = {};
#pragma unroll
    for (int k0 = 0; k0 < DKH; k0 += 32) {
      bf16x8 af[4], bf[4];
#pragma unroll
      for (int i = 0; i < 4; i++) {
        af[i] = *(const bf16x8*)&Qs[(wm + i * 16 + c16) * DKH + k0 + quad * 8];
        bf[i] = *(const bf16x8*)&Ks[(wn + i * 16 + c16) * DKH + k0 + quad * 8];
      }
#pragma unroll
      for (int mi = 0; mi < 4; mi++)
#pragma unroll
        for (int ni = 0; ni < 4; ni++)
          accs[mi][ni] = __builtin_amdgcn_mfma_f32_16x16x32_bf16(af[mi], bf[ni], accs[mi][ni], 0, 0, 0);
    }
    __syncthreads();

    if (t < 128) rowsum[t] = 0.f;
    __syncthreads();

#pragma unroll
    for (int mi = 0; mi < 4; mi++) {
      float rs[4] = {0.f, 0.f, 0.f, 0.f};
#pragma unroll
      for (int ni = 0; ni < 4; ni++) {
        const int j = wn + ni * 16 + c16;
#pragma unroll
        for (int r = 0; r < 4; r++) {
          const int i = wm + mi * 16 + quad * 4 + r;
          const float s = accs[mi][ni][r] * 0.125f;
          const float wv = (j <= i) ? (__expf(s) - 1.f) : 0.f;
          Ws[i * 128 + j] = (__bf16)wv;
          rs[r] += wv;
        }
      }
#pragma unroll
      for (int m = 1; m < 16; m <<= 1)
#pragma unroll
        for (int r = 0; r < 4; r++) rs[r] += __shfl_xor(rs[r], m);
      if (c16 == 0) {
#pragma unroll
        for (int r = 0; r < 4; r++)
          atomicAdd(&rowsum[wm + mi * 16 + quad * 4 + r], rs[r]);
      }
    }

    {
      const int j = t & 127;
      const int dh = (t >> 7) * 32;
      const __bf16* vp = qkv + base + 2 * EDIM + (size_t)j * QKV_LD + dh;
#pragma unroll
      for (int u = 0; u < 4; u++) {
        bf16x8 vv = *(const bf16x8*)(vp + u * 8);
#pragma unroll
        for (int x2 = 0; x2 < 8; x2++) Vt[(dh + u * 8 + x2) * 128 + j] = vv[x2];
      }
    }
    __syncthreads();

    f32x4 acco[2][4] = {};
#pragma unroll
    for (int j0 = 0; j0 < 128; j0 += 32) {
      bf16x8 af2[2], bf2[4];
#pragma unroll
      for (int mi = 0; mi < 2; mi++)
        af2[mi] = *(const bf16x8*)&Ws[(wid * 32 + mi * 16 + c16) * 128 + j0 + quad * 8];
#pragma unroll
      for (int ni = 0; ni < 4; ni++)
        bf2[ni] = *(const bf16x8*)&Vt[(ni * 16 + c16) * 128 + j0 + quad * 8];
#pragma unroll
      for (int mi = 0; mi < 2; mi++)
#pragma unroll
        for (int ni = 0; ni < 4; ni++)
          acco[mi][ni] = __builtin_amdgcn_mfma_f32_16x16x32_bf16(af2[mi], bf2[ni], acco[mi][ni], 0, 0, 0);
    }

#pragma unroll
    for (int mi = 0; mi < 2; mi++) {
#pragma unroll
      for (int ni = 0; ni < 4; ni++) {
        const int d = ni * 16 + c16;
        const float vt = vtot[h * DKH + d];
#pragma unroll
        for (int r = 0; r < 4; r++) {
          const int i = wid * 32 + mi * 16 + quad * 4 + r;
          const float denom = rowsum[i] + (float)N_TOK;
          const float val = (acco[mi][ni][r] + vt) / denom;
          out_attn[(size_t)(w * WSZ + i) * EDIM + h * DKH + d] = (__bf16)val;
        }
      }
    }
  } else {
    // ---- CEMA passC with inlined group scan (B2) ----
    const int bb = b - 256;
    const int c = bb >> 1;
    const int e = ((bb & 1) << 8) + t;
    const int g = c >> 4, j = c & 15;  // block-uniform
    float p[16], q[16], gm[16], h[16], Sv[16], Q32[16], Q512[16];
#pragma unroll
    for (int d4 = 0; d4 < 4; d4++) {
      const float4 pv = ((const float4*)(pc + e * 16))[d4];
      const float4 qv = ((const float4*)(qc + e * 16))[d4];
      const float4 gv = ((const float4*)(gma + e * 16))[d4];
      p[d4 * 4 + 0] = pv.x; p[d4 * 4 + 1] = pv.y; p[d4 * 4 + 2] = pv.z; p[d4 * 4 + 3] = pv.w;
      q[d4 * 4 + 0] = qv.x; q[d4 * 4 + 1] = qv.y; q[d4 * 4 + 2] = qv.z; q[d4 * 4 + 3] = qv.w;
      gm[d4 * 4 + 0] = gv.x; gm[d4 * 4 + 1] = gv.y; gm[d4 * 4 + 2] = gv.z; gm[d4 * 4 + 3] = gv.w;
    }
#pragma unroll
    for (int d = 0; d < 16; d++) {
      float Q = q[d] * q[d]; Q = Q * Q; Q = Q * Q; Q = Q * Q; Q = Q * Q;  // q^32
      Q32[d] = Q;
      float Q5 = Q * Q; Q5 = Q5 * Q5; Q5 = Q5 * Q5; Q5 = Q5 * Q5;        // q^512
      Q512[d] = Q5;
      Sv[d] = 0.f;
    }
    for (int gg = 0; gg < g; gg++) {
      const float* Tp = T + (size_t)gg * 8192 + e * 16;
#pragma unroll
      for (int d = 0; d < 16; d++) Sv[d] = Tp[d] + Q512[d] * Sv[d];
    }
    const float* hi = hin + (size_t)c * 8192 + e * 16;
#pragma unroll
    for (int d = 0; d < 16; d++) {
      float Qj = 1.f;
      for (int jj = 0; jj < j; jj++) Qj *= Q32[d];
      h[d] = hi[d] + Qj * Sv[d];
    }
    const float* xp = x + (size_t)c * CLEN * EDIM + e;
    float* yp = y + (size_t)c * CLEN * EDIM + e;
#pragma unroll 4
    for (int tt = 0; tt < CLEN; tt++) {
      const float xv = xp[(size_t)tt * EDIM];
      float acc = 0.f;
#pragma unroll
      for (int d = 0; d < 16; d++) {
        h[d] = fmaf(p[d], xv, q[d] * h[d]);
        acc = fmaf(gm[d], h[d], acc);
      }
      yp[(size_t)tt * EDIM] = acc;
    }
  }
}

// ================= L4: out-projection GEMM, fused adaptive mix, fp32 store =================
// M=4096 N=512 K=512; BM=128 BN=64 -> 32x8 = 256 blocks = exactly 1/CU.
__global__ __launch_bounds__(256) void gemm_out_kernel(const __bf16* __restrict__ A,
                                                       const __bf16* __restrict__ Bt,
                                                       const float* __restrict__ bias,
                                                       float* __restrict__ Cf,
                                                       const float* __restrict__ cema,
                                                       const float* __restrict__ aw) {
  gemm_body<1, 128, 64, 64, 32>(A, Bt, bias, nullptr, Cf, EDIM, EDIM, cema, aw,
                                blockIdx.x, blockIdx.y, threadIdx.x);
}

// ---------------- launch ----------------
extern "C" void kernel_launch(void* const* d_in, const int* in_sizes, int n_in,
                              void* d_out, int out_size, void* d_ws, size_t ws_size,
                              hipStream_t stream) {
  const float* x       = (const float*)d_in[0];
  const float* W_qkv   = (const float*)d_in[1];
  const float* b_qkv   = (const float*)d_in[2];
  const float* W_out   = (const float*)d_in[3];
  const float* b_out   = (const float*)d_in[4];
  // d_in[5] = omega (unused by reference)
  const float* p_coeff = (const float*)d_in[6];
  const float* q_coeff = (const float*)d_in[7];
  const float* gamma   = (const float*)d_in[8];
  const float* aw      = (const float*)d_in[9];

  char* ws = (char*)d_ws;
  __bf16* qkv      = (__bf16*)(ws);                 // 12,582,912
  __bf16* WtQ      = (__bf16*)(ws + 12582912);      //  1,572,864
  __bf16* WtO      = (__bf16*)(ws + 14155776);      //    524,288
  __bf16* out_attn = (__bf16*)(ws + 14680064);      //  4,194,304
  float*  vtot     = (float*) (ws + 18874368);      //      2,048
  float*  h_end    = (float*) (ws + 18876416);      //  4,194,304
  float*  hin      = (float*) (ws + 23070720);      //  4,194,304 (local prefixes)
  float*  y        = (float*) (ws + 27265024);      //  8,388,608
  __bf16* x_bf     = (__bf16*)(ws + 35653632);      //  4,194,304
  float*  xsum     = (float*) (ws + 39847936);      //      2,048
  float*  Tg       = (float*) (ws + 39849984);      //    262,144  (end ~40.1 MB)

  (void)hipMemsetAsync(xsum, 0, 512 * sizeof(float), stream);

  fused_prep_cemaA<<<512, 256, 0, stream>>>(W_qkv, WtQ, W_out, WtO,
                                            x, p_coeff, q_coeff, h_end, x_bf, xsum);

  fused_qkv_scan_vtot<<<768, 256, 0, stream>>>(x_bf, WtQ, b_qkv, qkv,
                                               q_coeff, h_end, hin, Tg, xsum, vtot);

  fused_attn_cemaC<<<512, 256, 0, stream>>>(qkv, vtot, out_attn,
                                            x, p_coeff, q_coeff, gamma, hin, Tg, y);

  gemm_out_kernel<<<dim3(32, 8), 256, 0, stream>>>(out_attn, WtO, b_out,
                                                   (float*)d_out, y, aw);
}

// Round 8
// 125.262 us; speedup vs baseline: 1.0830x; 1.0830x over previous
//
#include <hip/hip_runtime.h>
#include <hip/hip_bf16.h>

// MultiHeadAttention_66340064854505 — MI355X/gfx950
// B=1, N=4096, E=512, H=8, dk=64, WS=128, NDIM=16.
// ALL inputs/outputs FP32 (reference dtype). MFMA path converts to bf16.
//
// Identity (multiplicative block-causal mask into FULL-row softmax):
//   masked entries contribute exp(0)=1, so
//   out[i] = (Sum_{j<=i in blk}(e^s-1) v_j + V_total) / (Sum_{j<=i in blk}(e^s-1) + N)
// V_total via colsum identity: Sum_rows(x@Wv+b) = (Sum_rows x)@Wv + N*b.
// CEMA: 3-level scan (chunk 32 / group 16 / groups 8), fp32 exact; B2 inlined in passC.
// 4 dispatches: L1(prep||passA), L2(qkvGEMM||passB1||vtot), L3(attn||passC), L4(outGEMM).
// R8: reverted BK=64 (128B LDS row stride -> quad-uniform banks -> 16-way conflict, +8us);
//     memset dispatch removed via per-chunk xpart partials reduced inside vtot branch.

typedef __bf16 bf16x8 __attribute__((ext_vector_type(8)));
typedef float  f32x4  __attribute__((ext_vector_type(4)));

#define N_TOK   4096
#define EDIM    512
#define DKH     64
#define WSZ     128
#define QKV_LD  1536
#define CCH     128   // CEMA chunks
#define CLEN    32    // CEMA chunk length

__device__ __forceinline__ void glds16(const void* gsrc, void* ldst) {
  __builtin_amdgcn_global_load_lds(
      (const __attribute__((address_space(1))) void*)gsrc,
      (__attribute__((address_space(3))) void*)ldst,
      16, 0, 0);
}

// ---------------- shared GEMM body: C[M,N] = A[M,K](bf16) * Bt[N,K]^T + bias(f32) ----------------
// 256 thr = 4 waves tiled (BM/WM)x(BN/WN) (must be 4). 16x16x32 bf16 MFMA, BK=32.
// LDS row stride 64B: fragment ds_read_b128 uses all 32 banks at the 8-access floor.
// MODE 0: store bf16 to Cb.  MODE 1: store f32 w0*(gemm+bias)+w1*cema to Cf.
template <int MODE, int BM, int BN, int WM, int WN>
__device__ __forceinline__ void gemm_body(const __bf16* __restrict__ A,
                                          const __bf16* __restrict__ Bt,
                                          const float* __restrict__ bias,
                                          __bf16* __restrict__ Cb,
                                          float* __restrict__ Cf,
                                          int K, int ldc,
                                          const float* __restrict__ cema,
                                          const float* __restrict__ aw,
                                          int bx, int by, int t) {
  __shared__ __bf16 As[BM * 32];
  __shared__ __bf16 Bs[BN * 32];
  const int lane = t & 63, wid = t >> 6;
  const int quad = lane >> 4, c16 = lane & 15;
  const int wm = (wid % (BM / WM)) * WM, wn = (wid / (BM / WM)) * WN;
  const int m0 = bx * BM, n0 = by * BN;

  f32x4 acc[WM / 16][WN / 16] = {};

  const int ar = t >> 2, ac = (t & 3) * 8;
  const __bf16* gA = A + (size_t)(m0 + ar) * K + ac;
  const __bf16* gB = Bt + (size_t)(n0 + ar) * K + ac;

  for (int k0 = 0; k0 < K; k0 += 32) {
#pragma unroll
    for (int i = 0; i < BM / 64; i++)
      glds16(gA + (size_t)i * 64 * K + k0, As + i * 2048 + t * 8);
#pragma unroll
    for (int i = 0; i < BN / 64; i++)
      glds16(gB + (size_t)i * 64 * K + k0, Bs + i * 2048 + t * 8);
    __syncthreads();
    bf16x8 af[WM / 16], bf[WN / 16];
#pragma unroll
    for (int i = 0; i < WM / 16; i++)
      af[i] = *(const bf16x8*)&As[(wm + i * 16 + c16) * 32 + quad * 8];
#pragma unroll
    for (int i = 0; i < WN / 16; i++)
      bf[i] = *(const bf16x8*)&Bs[(wn + i * 16 + c16) * 32 + quad * 8];
#pragma unroll
    for (int mi = 0; mi < WM / 16; mi++)
#pragma unroll
      for (int ni = 0; ni < WN / 16; ni++)
        acc[mi][ni] = __builtin_amdgcn_mfma_f32_16x16x32_bf16(af[mi], bf[ni], acc[mi][ni], 0, 0, 0);
    __syncthreads();
  }

  float w0 = 1.f, w1 = 0.f;
  if (MODE == 1) {
    float a0 = aw[0], a1 = aw[1];
    float mx = fmaxf(a0, a1);
    float e0 = __expf(a0 - mx), e1 = __expf(a1 - mx);
    w0 = e0 / (e0 + e1);
    w1 = 1.f - w0;
  }
#pragma unroll
  for (int mi = 0; mi < WM / 16; mi++) {
#pragma unroll
    for (int ni = 0; ni < WN / 16; ni++) {
      const int col = n0 + wn + ni * 16 + c16;
      const float bv = bias[col];
#pragma unroll
      for (int r = 0; r < 4; r++) {
        const int row = m0 + wm + mi * 16 + quad * 4 + r;
        float v = acc[mi][ni][r] + bv;
        if (MODE == 1) {
          v = w0 * v + w1 * cema[(size_t)row * EDIM + col];
          Cf[(size_t)row * ldc + col] = v;
        } else {
          Cb[(size_t)row * ldc + col] = (__bf16)v;
        }
      }
    }
  }
}

// ================= L1: weight prep (blocks 0..255) || CEMA passA (blocks 256..511) =================
__global__ __launch_bounds__(256) void fused_prep_cemaA(const float* __restrict__ Wq,
                                                        __bf16* __restrict__ WtQ,
                                                        const float* __restrict__ Wo,
                                                        __bf16* __restrict__ WtO,
                                                        const float* __restrict__ x,
                                                        const float* __restrict__ pc,
                                                        const float* __restrict__ qc,
                                                        float* __restrict__ h_end,
                                                        __bf16* __restrict__ x_bf,
                                                        float* __restrict__ xpart) {
  const int b = blockIdx.x, t = threadIdx.x;
  if (b < 256) {
    // transpose+convert fp32 RxC -> bf16 CxR, 64x64 tiles. bx<24: W_qkv, else W_out.
    __shared__ float tile[64][65];
    int bx = b & 31;
    const int by = b >> 5;
    const float* in;
    __bf16* out;
    int C;
    if (bx < 24) { in = Wq; out = WtQ; C = 1536; }
    else         { bx -= 24; in = Wo; out = WtO; C = 512; }
    const int R = 512;
#pragma unroll
    for (int i = 0; i < 16; i++) {
      int idx = t + i * 256;
      int r = idx >> 6, c = idx & 63;
      tile[r][c] = in[(size_t)(by * 64 + r) * C + bx * 64 + c];
    }
    __syncthreads();
#pragma unroll
    for (int i = 0; i < 16; i++) {
      int idx = t + i * 256;
      int r = idx >> 6, c = idx & 63;
      out[(size_t)(bx * 64 + r) * R + by * 64 + c] = (__bf16)tile[c][r];
    }
  } else {
    // CEMA passA: chunk-local scan; also emits x_bf and xpart (per-chunk column partials).
    const int bb = b - 256;
    const int c = bb >> 1;
    const int e = ((bb & 1) << 8) + t;
    float p[16], q[16], h[16];
#pragma unroll
    for (int d4 = 0; d4 < 4; d4++) {
      const float4 pv = ((const float4*)(pc + e * 16))[d4];
      const float4 qv = ((const float4*)(qc + e * 16))[d4];
      p[d4 * 4 + 0] = pv.x; p[d4 * 4 + 1] = pv.y; p[d4 * 4 + 2] = pv.z; p[d4 * 4 + 3] = pv.w;
      q[d4 * 4 + 0] = qv.x; q[d4 * 4 + 1] = qv.y; q[d4 * 4 + 2] = qv.z; q[d4 * 4 + 3] = qv.w;
    }
#pragma unroll
    for (int d = 0; d < 16; d++) h[d] = 0.f;
    const float* xp = x + (size_t)c * CLEN * EDIM + e;
    __bf16* xb = x_bf + (size_t)c * CLEN * EDIM + e;
    float sx = 0.f;
#pragma unroll 4
    for (int tt = 0; tt < CLEN; tt++) {
      const float xv = xp[(size_t)tt * EDIM];
      xb[(size_t)tt * EDIM] = (__bf16)xv;
      sx += xv;
#pragma unroll
      for (int d = 0; d < 16; d++) h[d] = fmaf(p[d], xv, q[d] * h[d]);
    }
    xpart[(size_t)c * 512 + e] = sx;
    float* o = h_end + (size_t)c * 8192 + e * 16;
#pragma unroll
    for (int d = 0; d < 16; d++) o[d] = h[d];
  }
}

// ======= L2: QKV GEMM (0..383) || CEMA passB1 (384..639) || vtot (640..655) =======
__global__ __launch_bounds__(256) void fused_qkv_scan_vtot(const __bf16* __restrict__ x_bf,
                                                           const __bf16* __restrict__ WtQ,
                                                           const float* __restrict__ b_qkv,
                                                           __bf16* __restrict__ qkv,
                                                           const float* __restrict__ qc,
                                                           const float* __restrict__ h_end,
                                                           float* __restrict__ hin,
                                                           float* __restrict__ T,
                                                           const float* __restrict__ xpart,
                                                           float* __restrict__ vtot) {
  const int b = blockIdx.x, t = threadIdx.x;
  if (b < 384) {
    // M=4096 N=1536 K=512, BM=BN=128 -> 32 x 12 tiles
    gemm_body<0, 128, 128, 64, 64>(x_bf, WtQ, b_qkv, qkv, nullptr,
                                   EDIM, QKV_LD, nullptr, nullptr,
                                   b & 31, b >> 5, t);
  } else if (b < 640) {
    // passB1: per (group g of 16 chunks, channel i) local scan -> hin prefix + group total T
    const int idx = (b - 384) * 256 + t;  // 0..65535
    const int g = idx >> 13;              // 0..7
    const int i = idx & 8191;
    const float q = qc[i];
    float Q = q * q; Q = Q * Q; Q = Q * Q; Q = Q * Q; Q = Q * Q;  // q^32
    float L = 0.f;
    const int c0 = g * 16;
#pragma unroll 4
    for (int j = 0; j < 16; j++) {
      hin[(size_t)(c0 + j) * 8192 + i] = L;
      L = h_end[(size_t)(c0 + j) * 8192 + i] + Q * L;
    }
    T[(size_t)g * 8192 + i] = L;
  } else {
    // vtot: 16 blocks. Reduce xpart -> LDS xsum, then vtot[c] = dot(WtQ_v[c], xsum) + N*b.
    __shared__ float xs[512];
    float s0 = 0.f, s1 = 0.f;
    for (int c = 0; c < CCH; c++) {
      s0 += xpart[(size_t)c * 512 + t];
      s1 += xpart[(size_t)c * 512 + 256 + t];
    }
    xs[t] = s0; xs[256 + t] = s1;
    __syncthreads();
    const int wid = t >> 6, lane = t & 63;
#pragma unroll
    for (int u = 0; u < 8; u++) {
      const int c = (b - 640) * 32 + wid * 8 + u;  // [0,512)
      const bf16x8 wv = *(const bf16x8*)(WtQ + (size_t)(1024 + c) * 512 + lane * 8);
      float s = 0.f;
#pragma unroll
      for (int z = 0; z < 8; z++) s = fmaf((float)wv[z], xs[lane * 8 + z], s);
#pragma unroll
      for (int m = 1; m < 64; m <<= 1) s += __shfl_xor(s, m);
      if (lane == 0) vtot[c] = s + (float)N_TOK * b_qkv[1024 + c];
    }
  }
}

// ================= L3: attention (blocks 0..255) || CEMA passC+B2 (256..511) =================
__global__ __launch_bounds__(256) void fused_attn_cemaC(const __bf16* __restrict__ qkv,
                                                        const float* __restrict__ vtot,
                                                        __bf16* __restrict__ out_attn,
                                                        const float* __restrict__ x,
                                                        const float* __restrict__ pc,
                                                        const float* __restrict__ qc,
                                                        const float* __restrict__ gma,
                                                        const float* __restrict__ hin,
                                                        const float* __restrict__ T,
                                                        float* __restrict__ y) {
  const int b = blockIdx.x, t = threadIdx.x;
  if (b < 256) {
    // ---- block-local attention, one block per (window, head) ----
    // LDS (48.5 KB): phase1 Qs[0,16K) Ks[16K,32K); phase2 Ws[0,32K) Vt[32K,48K) rowsum[48K,48.5K)
    __shared__ float4 smem4[3104];
    __bf16* Qs = (__bf16*)smem4;
    __bf16* Ks = (__bf16*)smem4 + 8192;
    __bf16* Ws = (__bf16*)smem4;
    __bf16* Vt = (__bf16*)smem4 + 16384;
    float* rowsum = (float*)((__bf16*)smem4 + 24576);

    const int lane = t & 63, wid = t >> 6;
    const int quad = lane >> 4, c16 = lane & 15;
    const int h = b & 7, w = b >> 3;
    const size_t base = (size_t)w * WSZ * QKV_LD + h * DKH;

    const int sr = t >> 3, sc = (t & 7) * 8;
#pragma unroll
    for (int i = 0; i < 4; i++) {
      glds16(qkv + base + (size_t)(i * 32 + sr) * QKV_LD + sc,        Qs + i * 2048 + t * 8);
      glds16(qkv + base + EDIM + (size_t)(i * 32 + sr) * QKV_LD + sc, Ks + i * 2048 + t * 8);
    }
    __syncthreads();

    const int wm = (wid & 1) * 64, wn = (wid >> 1) * 64;
    f32x4 accs[4][4] = {};
#pragma unroll
    for (int k0 = 0; k0 < DKH; k0 += 32) {
      bf16x8 af[4], bf[4];
#pragma unroll
      for (int i = 0; i < 4; i++) {
        af[i] = *(const bf16x8*)&Qs[(wm + i * 16 + c16) * DKH + k0 + quad * 8];
        bf[i] = *(const bf16x8*)&Ks[(wn + i * 16 + c16) * DKH + k0 + quad * 8];
      }
#pragma unroll
      for (int mi = 0; mi < 4; mi++)
#pragma unroll
        for (int ni = 0; ni < 4; ni++)
          accs[mi][ni] = __builtin_amdgcn_mfma_f32_16x16x32_bf16(af[mi], bf[ni], accs[mi][ni], 0, 0, 0);
    }
    __syncthreads();

    if (t < 128) rowsum[t] = 0.f;
    __syncthreads();

#pragma unroll
    for (int mi = 0; mi < 4; mi++) {
      float rs[4] = {0.f, 0.f, 0.f, 0.f};
#pragma unroll
      for (int ni = 0; ni < 4; ni++) {
        const int j = wn + ni * 16 + c16;
#pragma unroll
        for (int r = 0; r < 4; r++) {
          const int i = wm + mi * 16 + quad * 4 + r;
          const float s = accs[mi][ni][r] * 0.125f;
          const float wv = (j <= i) ? (__expf(s) - 1.f) : 0.f;
          Ws[i * 128 + j] = (__bf16)wv;
          rs[r] += wv;
        }
      }
#pragma unroll
      for (int m = 1; m < 16; m <<= 1)
#pragma unroll
        for (int r = 0; r < 4; r++) rs[r] += __shfl_xor(rs[r], m);
      if (c16 == 0) {
#pragma unroll
        for (int r = 0; r < 4; r++)
          atomicAdd(&rowsum[wm + mi * 16 + quad * 4 + r], rs[r]);
      }
    }

    {
      const int j = t & 127;
      const int dh = (t >> 7) * 32;
      const __bf16* vp = qkv + base + 2 * EDIM + (size_t)j * QKV_LD + dh;
#pragma unroll
      for (int u = 0; u < 4; u++) {
        bf16x8 vv = *(const bf16x8*)(vp + u * 8);
#pragma unroll
        for (int x2 = 0; x2 < 8; x2++) Vt[(dh + u * 8 + x2) * 128 + j] = vv[x2];
      }
    }
    __syncthreads();

    f32x4 acco[2][4] = {};
#pragma unroll
    for (int j0 = 0; j0 < 128; j0 += 32) {
      bf16x8 af2[2], bf2[4];
#pragma unroll
      for (int mi = 0; mi < 2; mi++)
        af2[mi] = *(const bf16x8*)&Ws[(wid * 32 + mi * 16 + c16) * 128 + j0 + quad * 8];
#pragma unroll
      for (int ni = 0; ni < 4; ni++)
        bf2[ni] = *(const bf16x8*)&Vt[(ni * 16 + c16) * 128 + j0 + quad * 8];
#pragma unroll
      for (int mi = 0; mi < 2; mi++)
#pragma unroll
        for (int ni = 0; ni < 4; ni++)
          acco[mi][ni] = __builtin_amdgcn_mfma_f32_16x16x32_bf16(af2[mi], bf2[ni], acco[mi][ni], 0, 0, 0);
    }

#pragma unroll
    for (int mi = 0; mi < 2; mi++) {
#pragma unroll
      for (int ni = 0; ni < 4; ni++) {
        const int d = ni * 16 + c16;
        const float vt = vtot[h * DKH + d];
#pragma unroll
        for (int r = 0; r < 4; r++) {
          const int i = wid * 32 + mi * 16 + quad * 4 + r;
          const float denom = rowsum[i] + (float)N_TOK;
          const float val = (acco[mi][ni][r] + vt) / denom;
          out_attn[(size_t)(w * WSZ + i) * EDIM + h * DKH + d] = (__bf16)val;
        }
      }
    }
  } else {
    // ---- CEMA passC with inlined group scan (B2) ----
    const int bb = b - 256;
    const int c = bb >> 1;
    const int e = ((bb & 1) << 8) + t;
    const int g = c >> 4, j = c & 15;  // block-uniform
    float p[16], q[16], gm[16], h[16], Sv[16], Q32[16], Q512[16];
#pragma unroll
    for (int d4 = 0; d4 < 4; d4++) {
      const float4 pv = ((const float4*)(pc + e * 16))[d4];
      const float4 qv = ((const float4*)(qc + e * 16))[d4];
      const float4 gv = ((const float4*)(gma + e * 16))[d4];
      p[d4 * 4 + 0] = pv.x; p[d4 * 4 + 1] = pv.y; p[d4 * 4 + 2] = pv.z; p[d4 * 4 + 3] = pv.w;
      q[d4 * 4 + 0] = qv.x; q[d4 * 4 + 1] = qv.y; q[d4 * 4 + 2] = qv.z; q[d4 * 4 + 3] = qv.w;
      gm[d4 * 4 + 0] = gv.x; gm[d4 * 4 + 1] = gv.y; gm[d4 * 4 + 2] = gv.z; gm[d4 * 4 + 3] = gv.w;
    }
#pragma unroll
    for (int d = 0; d < 16; d++) {
      float Q = q[d] * q[d]; Q = Q * Q; Q = Q * Q; Q = Q * Q; Q = Q * Q;  // q^32
      Q32[d] = Q;
      float Q5 = Q * Q; Q5 = Q5 * Q5; Q5 = Q5 * Q5; Q5 = Q5 * Q5;        // q^512
      Q512[d] = Q5;
      Sv[d] = 0.f;
    }
    for (int gg = 0; gg < g; gg++) {
      const float* Tp = T + (size_t)gg * 8192 + e * 16;
#pragma unroll
      for (int d = 0; d < 16; d++) Sv[d] = Tp[d] + Q512[d] * Sv[d];
    }
    const float* hi = hin + (size_t)c * 8192 + e * 16;
#pragma unroll
    for (int d = 0; d < 16; d++) {
      float Qj = 1.f;
      for (int jj = 0; jj < j; jj++) Qj *= Q32[d];
      h[d] = hi[d] + Qj * Sv[d];
    }
    const float* xp = x + (size_t)c * CLEN * EDIM + e;
    float* yp = y + (size_t)c * CLEN * EDIM + e;
#pragma unroll 4
    for (int tt = 0; tt < CLEN; tt++) {
      const float xv = xp[(size_t)tt * EDIM];
      float acc = 0.f;
#pragma unroll
      for (int d = 0; d < 16; d++) {
        h[d] = fmaf(p[d], xv, q[d] * h[d]);
        acc = fmaf(gm[d], h[d], acc);
      }
      yp[(size_t)tt * EDIM] = acc;
    }
  }
}

// ================= L4: out-projection GEMM, fused adaptive mix, fp32 store =================
__global__ __launch_bounds__(256) void gemm_out_kernel(const __bf16* __restrict__ A,
                                                       const __bf16* __restrict__ Bt,
                                                       const float* __restrict__ bias,
                                                       float* __restrict__ Cf,
                                                       const float* __restrict__ cema,
                                                       const float* __restrict__ aw) {
  gemm_body<1, 64, 64, 32, 32>(A, Bt, bias, nullptr, Cf, EDIM, EDIM, cema, aw,
                               blockIdx.x, blockIdx.y, threadIdx.x);
}

// ---------------- launch ----------------
extern "C" void kernel_launch(void* const* d_in, const int* in_sizes, int n_in,
                              void* d_out, int out_size, void* d_ws, size_t ws_size,
                              hipStream_t stream) {
  const float* x       = (const float*)d_in[0];
  const float* W_qkv   = (const float*)d_in[1];
  const float* b_qkv   = (const float*)d_in[2];
  const float* W_out   = (const float*)d_in[3];
  const float* b_out   = (const float*)d_in[4];
  // d_in[5] = omega (unused by reference)
  const float* p_coeff = (const float*)d_in[6];
  const float* q_coeff = (const float*)d_in[7];
  const float* gamma   = (const float*)d_in[8];
  const float* aw      = (const float*)d_in[9];

  char* ws = (char*)d_ws;
  __bf16* qkv      = (__bf16*)(ws);                 // 12,582,912
  __bf16* WtQ      = (__bf16*)(ws + 12582912);      //  1,572,864
  __bf16* WtO      = (__bf16*)(ws + 14155776);      //    524,288
  __bf16* out_attn = (__bf16*)(ws + 14680064);      //  4,194,304
  float*  vtot     = (float*) (ws + 18874368);      //      2,048
  float*  h_end    = (float*) (ws + 18876416);      //  4,194,304
  float*  hin      = (float*) (ws + 23070720);      //  4,194,304 (local prefixes)
  float*  y        = (float*) (ws + 27265024);      //  8,388,608
  __bf16* x_bf     = (__bf16*)(ws + 35653632);      //  4,194,304
  float*  Tg       = (float*) (ws + 39849984);      //    262,144
  float*  xpart    = (float*) (ws + 40112128);      //    262,144  (end ~40.4 MB)

  fused_prep_cemaA<<<512, 256, 0, stream>>>(W_qkv, WtQ, W_out, WtO,
                                            x, p_coeff, q_coeff, h_end, x_bf, xpart);

  fused_qkv_scan_vtot<<<656, 256, 0, stream>>>(x_bf, WtQ, b_qkv, qkv,
                                               q_coeff, h_end, hin, Tg, xpart, vtot);

  fused_attn_cemaC<<<512, 256, 0, stream>>>(qkv, vtot, out_attn,
                                            x, p_coeff, q_coeff, gamma, hin, Tg, y);

  gemm_out_kernel<<<dim3(64, 8), 256, 0, stream>>>(out_attn, WtO, b_out,
                                                   (float*)d_out, y, aw);
}